// Round 17
// baseline (99.072 us; speedup 1.0000x reference)
//
#include <hip/hip_runtime.h>

// ---------------------------------------------------------------------------
// x [2,256,64,64]  y [2,256,32,512]  z [2,128,32,512]  u [2,64,64] int
// wq1/wk1 [128,256,3,3]  wq2/wk2 [128,128,3,3]  biases [128]   out [2,4096,128]
//
// Single-plane f16 MFMA convs, fp32 accumulation. Activations halo-padded
// [B][H+2][IC/32][W+2][32] f16 (zero halos -> no bounds checks).
// Conv (R13 geometry): wave = 1 row x 32 px x 64 oc; block = 4 waves =
// 2 rows x 64 px x 64 oc; grid 640, XCD-swizzled; single 36.9 KB weight
// buffer staged via global_load_lds. ALL 18 B-fragments of an icb are
// prefetched into registers BEFORE the barriers (latency overlaps the
// barrier wait); the 9-step MFMA loop touches no global memory.
// 4 launches: prep, conv1, conv2, attn.
// ---------------------------------------------------------------------------

typedef __attribute__((ext_vector_type(8))) _Float16 f16x8;
typedef __attribute__((ext_vector_type(4))) float f32x4;
typedef __attribute__((ext_vector_type(8))) unsigned short us8;
typedef unsigned short u16;

#define MFMA16F(A, B, C) __builtin_amdgcn_mfma_f32_16x16x32_f16((A), (B), (C), 0, 0, 0)

// Weight layout (pre-swizzled, single plane): flat(rs,icb,ocq,j) =
//   rs*(ICB*4096) + icb*4096 + ocq*1024 + j,
// j = ((ocl*32 + ic) ^ ((ocl&7)<<3)), ocl in [0,32), ic in [0,32). (bijective)
// Activation layout: FL(b,hp,icb,wp,c) = (((b*H2+hp)*ICB+icb)*W2+wp)*32 + c.

// ---- merged prep: pack weights [0,384) + zero halos [384,511) + cvt [511,14847)
__global__ __launch_bounds__(256) void prep_k(
    const float* __restrict__ x, const float* __restrict__ y,
    const float* __restrict__ z,
    const float* __restrict__ wq1, const float* __restrict__ wq2,
    const float* __restrict__ wk1, const float* __restrict__ wk2,
    u16* __restrict__ pq1, u16* __restrict__ pq2,
    u16* __restrict__ pk1, u16* __restrict__ pk2,
    u16* __restrict__ ypad, u16* __restrict__ xpad,
    u16* __restrict__ t2k, u16* __restrict__ t1q,
    u16* __restrict__ zf16)
{
  __shared__ float tile[32][33];
  const int bid = blockIdx.x;
  const int tid = threadIdx.x;

  if (bid < 384) {
    // ---- pack all 4 weight tensors -> f16 single plane, swizzled layout
    int t = bid * 256 + tid;
    const float* w; u16* dst; int IC, tt;
    if (t < 32768)      { w = wq1; dst = pq1; IC = 256; tt = t; }
    else if (t < 49152) { w = wq2; dst = pq2; IC = 128; tt = t - 32768; }
    else if (t < 81920) { w = wk1; dst = pk1; IC = 256; tt = t - 49152; }
    else                { w = wk2; dst = pk2; IC = 128; tt = t - 81920; }
    const int oc = tt / IC, ic = tt % IC;
    const int ICB = IC >> 5;
    const int ocl = oc & 31, ocq = oc >> 5;
    const int icb = ic >> 5, icl = ic & 31;
    const int swz = ((ocl << 5) | icl) ^ ((ocl & 7) << 3);
    #pragma unroll
    for (int rs = 0; rs < 9; ++rs) {
      float v = w[(oc * IC + ic) * 9 + rs];
      long base = (long)rs * (ICB * 4096) + (long)icb * 4096
                + (long)ocq * 1024 + swz;
      dst[base] = __builtin_bit_cast(u16, (_Float16)v);
    }
  } else if (bid < 511) {
    // ---- zero halos: units of 32 u16. cum: ypad 17472, xpad 21632,
    // t2k 30368, t1q 32448.
    long u = (long)(bid - 384) * 256 + tid;
    if (u >= 32448) return;
    u16* p; int ICB, H, W2;
    if (u < 17472)      { p = ypad; ICB = 8; H = 32; W2 = 514; }
    else if (u < 21632) { u -= 17472; p = xpad; ICB = 8; H = 64; W2 = 66; }
    else if (u < 30368) { u -= 21632; p = t2k; ICB = 4; H = 32; W2 = 514; }
    else                { u -= 30368; p = t1q; ICB = 4; H = 64; W2 = 66; }
    const int H2 = H + 2;
    const long rowsN = (long)2 * ICB * 2 * W2;
    long base;
    if (u < rowsN) {
      int w = (int)(u % W2);
      int t2 = (int)(u / W2);
      int tb = t2 & 1, icb = (t2 >> 1) % ICB, b = (t2 >> 1) / ICB;
      int h = tb ? H2 - 1 : 0;
      base = ((((long)b * H2 + h) * ICB + icb) * W2 + w) * 32;
    } else {
      long v = u - rowsN;
      int side = (int)(v & 1);
      long v2 = v >> 1;
      int h = 1 + (int)(v2 % H);
      int icb = (int)((v2 / H) % ICB);
      int b = (int)(v2 / ((long)H * ICB));
      int w = side ? W2 - 1 : 0;
      base = ((((long)b * H2 + h) * ICB + icb) * W2 + w) * 32;
    }
    us8 zz = {0, 0, 0, 0, 0, 0, 0, 0};
    #pragma unroll
    for (int j = 0; j < 4; ++j)
      *reinterpret_cast<us8*>(&p[base + j * 8]) = zz;
  } else {
    // ---- transpose/cvt: y -> ypad, x -> xpad (f16 padded), z -> zf16
    const int id = bid - 511;
    const float* src; int C, H, W, wt, cb, bh, mode, H2, W2;
    u16* d16;
    if (id < 8192)       { src = y; C = 256; H = 32; W = 512; wt = id & 15;       cb = (id >> 4) & 7; bh = id >> 7; d16 = ypad; mode = 0; H2 = 34; W2 = 514; }
    else if (id < 10240) { int i2 = id - 8192;  src = x; C = 256; H = 64; W = 64; wt = i2 & 1;  cb = (i2 >> 1) & 7; bh = i2 >> 4; d16 = xpad; mode = 0; H2 = 66; W2 = 66; }
    else                 { int i3 = id - 10240; src = z; C = 128; H = 32; W = 512; wt = i3 & 15; cb = (i3 >> 4) & 3; bh = i3 >> 6; d16 = zf16; mode = 1; H2 = 0; W2 = 0; }
    const int b = bh / H, h = bh % H;
    const int w0 = wt * 32;
    const int tx = tid & 31, ty = tid >> 5;
    #pragma unroll
    for (int k2 = 0; k2 < 4; ++k2) {
      int c = cb * 32 + ty + k2 * 8;
      tile[ty + k2 * 8][tx] = src[(((long)b * C + c) * H + h) * W + w0 + tx];
    }
    __syncthreads();
    const int cp = (tid & 15) * 2;
    const int wl = tid >> 4;
    if (mode == 0) {
      const int ICB = C >> 5;
      #pragma unroll
      for (int half = 0; half < 2; ++half) {
        const int wloc = wl + half * 16;
        unsigned int lo = (unsigned int)__builtin_bit_cast(u16, (_Float16)tile[cp][wloc]);
        unsigned int hi = (unsigned int)__builtin_bit_cast(u16, (_Float16)tile[cp + 1][wloc]);
        long idx = ((((long)b * H2 + h + 1) * ICB + cb) * W2 + (w0 + wloc + 1)) * 32 + cp;
        *reinterpret_cast<unsigned int*>(&d16[idx]) = lo | (hi << 16);
      }
    } else {
      #pragma unroll
      for (int half = 0; half < 2; ++half) {
        const int wloc = wl + half * 16;
        unsigned int lo = (unsigned int)__builtin_bit_cast(u16, (_Float16)tile[cp][wloc]);
        unsigned int hi = (unsigned int)__builtin_bit_cast(u16, (_Float16)tile[cp + 1][wloc]);
        long idx = (((long)b * 32 + h) * 512 + (w0 + wloc)) * 128 + cb * 32 + cp;
        *reinterpret_cast<unsigned int*>(&d16[idx]) = lo | (hi << 16);
      }
    }
  }
}

// ---- merged conv (k wids [0,512) + q wids [512,640)).
// Block: 64 oc (ocsel) x 2 rows x 64 px; wave = 1 row x 32 px x 64 oc.
// XCD swizzle: wid = (bid%8)*80 + bid/8 (bijective, 640 % 8 == 0).
// Single 36.9 KB weight buffer via global_load_lds; B prefetched to regs.
// OF16=1: f16 padded out [B][IH+2][4][IW+2][32] + relu.
// OF16=0: f16 flat out [B][IH][IW][128].
template<int ICB, int OF16>
__global__ __launch_bounds__(256, 3) void conv_k(
    const u16* __restrict__ inK, const u16* __restrict__ wpkK,
    const float* __restrict__ biasK, u16* __restrict__ outK,
    const u16* __restrict__ inQ, const u16* __restrict__ wpkQ,
    const float* __restrict__ biasQ, u16* __restrict__ outQ)
{
  __shared__ __align__(16) u16 smem[18432];   // 36864 B: 9 rs x 2 tiles x 1024

  const int tid = threadIdx.x;
  const int lane = tid & 63, wv = tid >> 6;
  const int lm = lane & 15, lq = lane >> 4;
  const int bid = blockIdx.x;
  const int wid = (bid & 7) * 80 + (bid >> 3);

  const u16* in; const u16* wpk; const float* bias; u16* outp;
  int IH, IW, w0, hb, b, ocsel;
  if (wid < 512) {
    in = inK; wpk = wpkK; bias = biasK; outp = outK;
    IH = 32; IW = 512;
    b = wid >> 8; hb = ((wid >> 4) & 15) * 2;
    w0 = ((wid >> 1) & 7) * 64; ocsel = wid & 1;
  } else {
    const int qb = wid - 512;
    in = inQ; wpk = wpkQ; bias = biasQ; outp = outQ;
    IH = 64; IW = 64;
    b = qb >> 6; hb = ((qb >> 1) & 31) * 2;
    w0 = 0; ocsel = qb & 1;
  }
  const int H2 = IH + 2, W2 = IW + 2;
  const int rp = wv >> 1;               // wave's row within block (0..1)
  const int pxw = (wv & 1) * 32;        // wave's 32-px group

  // A-frag swizzled base; mf steps of +512 ((16k+lm)&7 == lm&7).
  const int aswz0 = (lm * 32 + lq * 8) ^ ((lm & 7) << 3);

  f32x4 acc[4][2];   // [mf][f]
  #pragma unroll
  for (int mf = 0; mf < 4; ++mf)
    #pragma unroll
    for (int f = 0; f < 2; ++f) acc[mf][f] = (f32x4)0.f;

  for (int icb = 0; icb < ICB; ++icb) {
    // ---- prefetch ALL 18 B fragments of this icb into registers (issued
    // before the barriers: latency hides under barrier wait + DMA drain)
    f16x8 bb[3][3][2];
    {
      const u16* rb[3];
      #pragma unroll
      for (int r = 0; r < 3; ++r) {
        rb[r] = in + ((((long)b * H2 + hb + rp + r) * ICB + icb) * W2 + (w0 + pxw + lm)) * 32
              + lq * 8;
        #pragma unroll
        for (int s = 0; s < 3; ++s)
          #pragma unroll
          for (int f = 0; f < 2; ++f)
            bb[r][s][f] = *reinterpret_cast<const f16x8*>(rb[r] + (f * 16 + s) * 32);
      }
    }
    __syncthreads();   // prior iter done reading smem
    // ---- stage this icb's 9 rs x 2 ocq-tiles via DMA (no VGPR round-trip)
    #pragma unroll
    for (int j = 0; j < 9; ++j) {
      const u16* g = wpk + (long)j * (ICB * 4096) + (long)icb * 4096
                   + ocsel * 2048 + wv * 512 + (lane << 3);
      u16* l = smem + j * 2048 + wv * 512;
      __builtin_amdgcn_global_load_lds(
          (const __attribute__((address_space(1))) unsigned int*)g,
          (__attribute__((address_space(3))) unsigned int*)l,
          16, 0, 0);
    }
    __syncthreads();   // drains vmcnt: staged weights (and B regs) ready

    #pragma unroll
    for (int r = 0; r < 3; ++r)
      #pragma unroll
      for (int s = 0; s < 3; ++s) {
        const int rs = r * 3 + s;
        const int base = rs * 2048 + aswz0;
        const f16x8 a0 = *reinterpret_cast<const f16x8*>(&smem[base]);
        const f16x8 a1 = *reinterpret_cast<const f16x8*>(&smem[base + 512]);
        const f16x8 a2 = *reinterpret_cast<const f16x8*>(&smem[base + 1024]);
        const f16x8 a3 = *reinterpret_cast<const f16x8*>(&smem[base + 1536]);
        acc[0][0] = MFMA16F(a0, bb[r][s][0], acc[0][0]);
        acc[0][1] = MFMA16F(a0, bb[r][s][1], acc[0][1]);
        acc[1][0] = MFMA16F(a1, bb[r][s][0], acc[1][0]);
        acc[1][1] = MFMA16F(a1, bb[r][s][1], acc[1][1]);
        acc[2][0] = MFMA16F(a2, bb[r][s][0], acc[2][0]);
        acc[2][1] = MFMA16F(a2, bb[r][s][1], acc[2][1]);
        acc[3][0] = MFMA16F(a3, bb[r][s][0], acc[3][0]);
        acc[3][1] = MFMA16F(a3, bb[r][s][1], acc[3][1]);
      }
  }

  // ---- epilogue: bias (+relu for OF16), LDS staging [2][64][72] (16B-align,
  // ~2-way banks), f16 write
  __syncthreads();
  u16* st = smem;
  #pragma unroll
  for (int mf = 0; mf < 4; ++mf)
    #pragma unroll
    for (int f = 0; f < 2; ++f)
      #pragma unroll
      for (int reg = 0; reg < 4; ++reg) {
        const int ocl = mf * 16 + lq * 4 + reg;    // 0..63
        const int px = pxw + f * 16 + lm;
        float v = acc[mf][f][reg] + bias[ocsel * 64 + ocl];
        if (OF16) v = fmaxf(v, 0.f);
        st[(rp * 64 + px) * 72 + ocl] = __builtin_bit_cast(u16, (_Float16)v);
      }
  __syncthreads();
  for (int i = tid; i < 1024; i += 256) {   // 2 rows x 64 px x 8 us8-chunks
    const int o8 = i & 7;
    const int px = (i >> 3) & 63;
    const int row = i >> 9;
    us8 val = *reinterpret_cast<const us8*>(&st[(row * 64 + px) * 72 + o8 * 8]);
    u16* dst;
    if (OF16)
      dst = outp + ((((long)b * H2 + hb + row + 1) * 4 + ocsel * 2 + (o8 >> 2)) * W2
                    + (w0 + px + 1)) * 32 + (o8 & 3) * 8;
    else
      dst = outp + (((long)b * IH + hb + row) * IW + w0 + px) * 128
          + ocsel * 64 + o8 * 8;
    *reinterpret_cast<us8*>(dst) = val;
  }
}

// ---- attention: one block per (b, n). 128 threads. All operands f16.
__global__ __launch_bounds__(128) void attn_k(
    const u16* __restrict__ qf, const u16* __restrict__ kf,
    const u16* __restrict__ zf, const int* __restrict__ u,
    float* __restrict__ out)
{
  constexpr float SCALE = 0.08838834764831845f;  // 128^-0.5
  const int n = blockIdx.x, b = blockIdx.y;
  const int t = threadIdx.x;

  __shared__ float qs[128];
  __shared__ float logit[32];
  __shared__ float el[32];

  int widx = u[b * 4096 + n];
  widx = widx < 0 ? 0 : (widx > 511 ? 511 : widx);

  qs[t] = (float)__builtin_bit_cast(_Float16, qf[((long)b * 4096 + n) * 128 + t]);
  __syncthreads();

  const int h = t >> 2, quad = t & 3;
  const u16* kcol = kf + (((long)b * 32 + h) * 512 + widx) * 128 + quad * 32;
  float p = 0.f;
  #pragma unroll
  for (int j = 0; j < 32; j += 8) {
    f16x8 kv = *reinterpret_cast<const f16x8*>(kcol + j);
    #pragma unroll
    for (int jj = 0; jj < 8; ++jj)
      p = fmaf(qs[quad * 32 + j + jj], (float)kv[jj], p);
  }
  p += __shfl_xor(p, 1);
  p += __shfl_xor(p, 2);
  if (quad == 0) logit[h] = p * SCALE;
  __syncthreads();

  float m = -3.4e38f;
  #pragma unroll
  for (int h2 = 0; h2 < 32; ++h2) m = fmaxf(m, logit[h2]);
  if (t < 32) el[t] = __expf(logit[t] - m);
  __syncthreads();
  float den = 0.f;
  #pragma unroll
  for (int h2 = 0; h2 < 32; ++h2) den += el[h2];

  const u16* zcol = zf + ((long)b * 32 * 512) * 128 + (long)widx * 128 + t;
  float o0 = 0.f, o1 = 0.f, o2 = 0.f, o3 = 0.f;
  #pragma unroll
  for (int h2 = 0; h2 < 32; h2 += 4) {
    o0 = fmaf(el[h2 + 0], (float)__builtin_bit_cast(_Float16, zcol[(long)(h2 + 0) * 512 * 128]), o0);
    o1 = fmaf(el[h2 + 1], (float)__builtin_bit_cast(_Float16, zcol[(long)(h2 + 1) * 512 * 128]), o1);
    o2 = fmaf(el[h2 + 2], (float)__builtin_bit_cast(_Float16, zcol[(long)(h2 + 2) * 512 * 128]), o2);
    o3 = fmaf(el[h2 + 3], (float)__builtin_bit_cast(_Float16, zcol[(long)(h2 + 3) * 512 * 128]), o3);
  }
  out[((long)b * 4096 + n) * 128 + t] = ((o0 + o1) + (o2 + o3)) / den;
}

extern "C" void kernel_launch(void* const* d_in, const int* in_sizes, int n_in,
                              void* d_out, int out_size, void* d_ws, size_t ws_size,
                              hipStream_t stream) {
  const float* x   = (const float*)d_in[0];
  const float* y   = (const float*)d_in[1];
  const float* z   = (const float*)d_in[2];
  const int*   u   = (const int*)  d_in[3];
  const float* wq1 = (const float*)d_in[4];
  const float* bq1 = (const float*)d_in[5];
  const float* wq2 = (const float*)d_in[6];
  const float* bq2 = (const float*)d_in[7];
  const float* wk1 = (const float*)d_in[8];
  const float* bk1 = (const float*)d_in[9];
  const float* wk2 = (const float*)d_in[10];
  const float* bk2 = (const float*)d_in[11];
  float* out = (float*)d_out;
  u16* wsu = (u16*)d_ws;

  // ---- arena (u16 offsets); total 54.2 MB
  u16* ypad  = wsu + 0;           //  8,947,712  [2][34][8][514][32] f16
  u16* xpad  = wsu + 8947712;     //  2,230,272  [2][66][8][66][32]  f16
  u16* t2k   = wsu + 11177984;    //  4,473,856  [2][34][4][514][32] f16
  u16* t1q   = wsu + 15651840;    //  1,115,136  [2][66][4][66][32]  f16
  u16* zf16  = wsu + 16766976;    //  4,194,304  [2][32][512][128]   f16
  u16* k_f16 = wsu + 20961280;    //  4,194,304  [2][32][512][128]   f16
  u16* q_f16 = wsu + 25155584;    //  1,048,576  [2,4096,128]        f16
  u16* wpk_q1 = wsu + 26204160;   //    294,912  (pre-swizzled)
  u16* wpk_q2 = wsu + 26499072;   //    147,456
  u16* wpk_k1 = wsu + 26646528;   //    294,912
  u16* wpk_k2 = wsu + 26941440;   //    147,456  -> end 27,088,896 u16

  prep_k<<<dim3(14847), 256, 0, stream>>>(x, y, z, wq1, wq2, wk1, wk2,
                                          wpk_q1, wpk_q2, wpk_k1, wpk_k2,
                                          ypad, xpad, t2k, t1q, zf16);
  conv_k<8, 1><<<dim3(640), 256, 0, stream>>>(
      ypad, wpk_k1, bk1, t2k, xpad, wpk_q1, bq1, t1q);
  conv_k<4, 0><<<dim3(640), 256, 0, stream>>>(
      t2k, wpk_k2, bk2, k_f16, t1q, wpk_q2, bq2, q_f16);
  attn_k<<<dim3(4096, 2), 128, 0, stream>>>(q_f16, k_f16, zf16, u, out);
}

// Round 18
// 94.787 us; speedup vs baseline: 1.0452x; 1.0452x over previous
//
#include <hip/hip_runtime.h>

// ---------------------------------------------------------------------------
// x [2,256,64,64]  y [2,256,32,512]  z [2,128,32,512]  u [2,64,64] int
// wq1/wk1 [128,256,3,3]  wq2/wk2 [128,128,3,3]  biases [128]   out [2,4096,128]
//
// Single-plane f16 MFMA convs, fp32 accumulation. Activations halo-padded
// [B][H+2][IC/32][W+2][32] f16 (zero halos -> no bounds checks).
// Conv: wave = 2 rows x 32 px x 64 oc (16 MFMA : 4 ds_read : 4 B-loads per
// rs — R14's per-wave efficiency) in 2-WAVE blocks (128 thr) = 2 rows x
// 64 px x 64 oc; grid 640 (R13's balanced distribution), XCD-swizzled.
// Weights (36.9 KB, capacity-4) staged via global_load_lds, 18 ops/thread.
// 4 launches: prep, conv1, conv2, attn.
// ---------------------------------------------------------------------------

typedef __attribute__((ext_vector_type(8))) _Float16 f16x8;
typedef __attribute__((ext_vector_type(4))) float f32x4;
typedef __attribute__((ext_vector_type(8))) unsigned short us8;
typedef unsigned short u16;

#define MFMA16F(A, B, C) __builtin_amdgcn_mfma_f32_16x16x32_f16((A), (B), (C), 0, 0, 0)

// Weight layout (pre-swizzled, single plane): flat(rs,icb,ocq,j) =
//   rs*(ICB*4096) + icb*4096 + ocq*1024 + j,
// j = ((ocl*32 + ic) ^ ((ocl&7)<<3)), ocl in [0,32), ic in [0,32). (bijective)
// Activation layout: FL(b,hp,icb,wp,c) = (((b*H2+hp)*ICB+icb)*W2+wp)*32 + c.

// ---- merged prep: pack weights [0,384) + zero halos [384,511) + cvt [511,14847)
__global__ __launch_bounds__(256) void prep_k(
    const float* __restrict__ x, const float* __restrict__ y,
    const float* __restrict__ z,
    const float* __restrict__ wq1, const float* __restrict__ wq2,
    const float* __restrict__ wk1, const float* __restrict__ wk2,
    u16* __restrict__ pq1, u16* __restrict__ pq2,
    u16* __restrict__ pk1, u16* __restrict__ pk2,
    u16* __restrict__ ypad, u16* __restrict__ xpad,
    u16* __restrict__ t2k, u16* __restrict__ t1q,
    u16* __restrict__ zf16)
{
  __shared__ float tile[32][33];
  const int bid = blockIdx.x;
  const int tid = threadIdx.x;

  if (bid < 384) {
    // ---- pack all 4 weight tensors -> f16 single plane, swizzled layout
    int t = bid * 256 + tid;
    const float* w; u16* dst; int IC, tt;
    if (t < 32768)      { w = wq1; dst = pq1; IC = 256; tt = t; }
    else if (t < 49152) { w = wq2; dst = pq2; IC = 128; tt = t - 32768; }
    else if (t < 81920) { w = wk1; dst = pk1; IC = 256; tt = t - 49152; }
    else                { w = wk2; dst = pk2; IC = 128; tt = t - 81920; }
    const int oc = tt / IC, ic = tt % IC;
    const int ICB = IC >> 5;
    const int ocl = oc & 31, ocq = oc >> 5;
    const int icb = ic >> 5, icl = ic & 31;
    const int swz = ((ocl << 5) | icl) ^ ((ocl & 7) << 3);
    #pragma unroll
    for (int rs = 0; rs < 9; ++rs) {
      float v = w[(oc * IC + ic) * 9 + rs];
      long base = (long)rs * (ICB * 4096) + (long)icb * 4096
                + (long)ocq * 1024 + swz;
      dst[base] = __builtin_bit_cast(u16, (_Float16)v);
    }
  } else if (bid < 511) {
    // ---- zero halos: units of 32 u16. cum: ypad 17472, xpad 21632,
    // t2k 30368, t1q 32448.
    long u = (long)(bid - 384) * 256 + tid;
    if (u >= 32448) return;
    u16* p; int ICB, H, W2;
    if (u < 17472)      { p = ypad; ICB = 8; H = 32; W2 = 514; }
    else if (u < 21632) { u -= 17472; p = xpad; ICB = 8; H = 64; W2 = 66; }
    else if (u < 30368) { u -= 21632; p = t2k; ICB = 4; H = 32; W2 = 514; }
    else                { u -= 30368; p = t1q; ICB = 4; H = 64; W2 = 66; }
    const int H2 = H + 2;
    const long rowsN = (long)2 * ICB * 2 * W2;
    long base;
    if (u < rowsN) {
      int w = (int)(u % W2);
      int t2 = (int)(u / W2);
      int tb = t2 & 1, icb = (t2 >> 1) % ICB, b = (t2 >> 1) / ICB;
      int h = tb ? H2 - 1 : 0;
      base = ((((long)b * H2 + h) * ICB + icb) * W2 + w) * 32;
    } else {
      long v = u - rowsN;
      int side = (int)(v & 1);
      long v2 = v >> 1;
      int h = 1 + (int)(v2 % H);
      int icb = (int)((v2 / H) % ICB);
      int b = (int)(v2 / ((long)H * ICB));
      int w = side ? W2 - 1 : 0;
      base = ((((long)b * H2 + h) * ICB + icb) * W2 + w) * 32;
    }
    us8 zz = {0, 0, 0, 0, 0, 0, 0, 0};
    #pragma unroll
    for (int j = 0; j < 4; ++j)
      *reinterpret_cast<us8*>(&p[base + j * 8]) = zz;
  } else {
    // ---- transpose/cvt: y -> ypad, x -> xpad (f16 padded), z -> zf16
    const int id = bid - 511;
    const float* src; int C, H, W, wt, cb, bh, mode, H2, W2;
    u16* d16;
    if (id < 8192)       { src = y; C = 256; H = 32; W = 512; wt = id & 15;       cb = (id >> 4) & 7; bh = id >> 7; d16 = ypad; mode = 0; H2 = 34; W2 = 514; }
    else if (id < 10240) { int i2 = id - 8192;  src = x; C = 256; H = 64; W = 64; wt = i2 & 1;  cb = (i2 >> 1) & 7; bh = i2 >> 4; d16 = xpad; mode = 0; H2 = 66; W2 = 66; }
    else                 { int i3 = id - 10240; src = z; C = 128; H = 32; W = 512; wt = i3 & 15; cb = (i3 >> 4) & 3; bh = i3 >> 6; d16 = zf16; mode = 1; H2 = 0; W2 = 0; }
    const int b = bh / H, h = bh % H;
    const int w0 = wt * 32;
    const int tx = tid & 31, ty = tid >> 5;
    #pragma unroll
    for (int k2 = 0; k2 < 4; ++k2) {
      int c = cb * 32 + ty + k2 * 8;
      tile[ty + k2 * 8][tx] = src[(((long)b * C + c) * H + h) * W + w0 + tx];
    }
    __syncthreads();
    const int cp = (tid & 15) * 2;
    const int wl = tid >> 4;
    if (mode == 0) {
      const int ICB = C >> 5;
      #pragma unroll
      for (int half = 0; half < 2; ++half) {
        const int wloc = wl + half * 16;
        unsigned int lo = (unsigned int)__builtin_bit_cast(u16, (_Float16)tile[cp][wloc]);
        unsigned int hi = (unsigned int)__builtin_bit_cast(u16, (_Float16)tile[cp + 1][wloc]);
        long idx = ((((long)b * H2 + h + 1) * ICB + cb) * W2 + (w0 + wloc + 1)) * 32 + cp;
        *reinterpret_cast<unsigned int*>(&d16[idx]) = lo | (hi << 16);
      }
    } else {
      #pragma unroll
      for (int half = 0; half < 2; ++half) {
        const int wloc = wl + half * 16;
        unsigned int lo = (unsigned int)__builtin_bit_cast(u16, (_Float16)tile[cp][wloc]);
        unsigned int hi = (unsigned int)__builtin_bit_cast(u16, (_Float16)tile[cp + 1][wloc]);
        long idx = (((long)b * 32 + h) * 512 + (w0 + wloc)) * 128 + cb * 32 + cp;
        *reinterpret_cast<unsigned int*>(&d16[idx]) = lo | (hi << 16);
      }
    }
  }
}

// ---- merged conv (k wids [0,512) + q wids [512,640)). 128 threads = 2 waves.
// Block: 64 oc (ocsel) x 2 rows x 64 px; wave = 2 rows x 32 px x 64 oc.
// XCD swizzle: wid = (bid%8)*80 + bid/8 (bijective, 640 % 8 == 0).
// Single 36.9 KB weight buffer via global_load_lds (18 DMA ops/thread).
// OF16=1: f16 padded out [B][IH+2][4][IW+2][32] + relu.
// OF16=0: f16 flat out [B][IH][IW][128].
template<int ICB, int OF16>
__global__ __launch_bounds__(128, 2) void conv_k(
    const u16* __restrict__ inK, const u16* __restrict__ wpkK,
    const float* __restrict__ biasK, u16* __restrict__ outK,
    const u16* __restrict__ inQ, const u16* __restrict__ wpkQ,
    const float* __restrict__ biasQ, u16* __restrict__ outQ)
{
  __shared__ __align__(16) u16 smem[18432];   // 36864 B: 9 rs x 2048 u16

  const int tid = threadIdx.x;
  const int lane = tid & 63, wv = tid >> 6;   // wv in {0,1}
  const int lm = lane & 15, lq = lane >> 4;
  const int bid = blockIdx.x;
  const int wid = (bid & 7) * 80 + (bid >> 3);

  const u16* in; const u16* wpk; const float* bias; u16* outp;
  int IH, IW, w0, hb, b, ocsel;
  if (wid < 512) {
    in = inK; wpk = wpkK; bias = biasK; outp = outK;
    IH = 32; IW = 512;
    b = wid >> 8; hb = ((wid >> 4) & 15) * 2;
    w0 = ((wid >> 1) & 7) * 64; ocsel = wid & 1;
  } else {
    const int qb = wid - 512;
    in = inQ; wpk = wpkQ; bias = biasQ; outp = outQ;
    IH = 64; IW = 64;
    b = qb >> 6; hb = ((qb >> 1) & 31) * 2;
    w0 = 0; ocsel = qb & 1;
  }
  const int H2 = IH + 2, W2 = IW + 2;
  const int pxw = wv * 32;              // wave's 32-px group (both rows)

  // A-frag swizzled base; mf steps of +512 ((16k+lm)&7 == lm&7).
  const int aswz0 = (lm * 32 + lq * 8) ^ ((lm & 7) << 3);

  f32x4 acc[4][2][2];   // [mf][jj(row)][f]
  #pragma unroll
  for (int mf = 0; mf < 4; ++mf)
    #pragma unroll
    for (int jj = 0; jj < 2; ++jj)
      #pragma unroll
      for (int f = 0; f < 2; ++f) acc[mf][jj][f] = (f32x4)0.f;

  for (int icb = 0; icb < ICB; ++icb) {
    __syncthreads();   // prior iter done reading smem
    // ---- stage this icb's 9 rs-tiles (2048 u16 each) via DMA.
    // Op j covers u16 [j*1024,(j+1)*1024): rs = j>>1, part = j&1.
    // Dest = wave-uniform base + lane*16 (tid*8 u16); src per-lane global.
    #pragma unroll
    for (int j = 0; j < 18; ++j) {
      const int rs2 = j >> 1, part = j & 1;
      const u16* g = wpk + (long)rs2 * (ICB * 4096) + (long)icb * 4096
                   + ocsel * 2048 + part * 1024 + tid * 8;
      u16* l = smem + rs2 * 2048 + part * 1024 + tid * 8;
      __builtin_amdgcn_global_load_lds(
          (const __attribute__((address_space(1))) unsigned int*)g,
          (__attribute__((address_space(3))) unsigned int*)l,
          16, 0, 0);
    }
    // ---- per-lane row base pointers (padded rows hb .. hb+3)
    const u16* rb[4];
    #pragma unroll
    for (int jr = 0; jr < 4; ++jr)
      rb[jr] = in + ((((long)b * H2 + hb + jr) * ICB + icb) * W2 + (w0 + pxw + lm)) * 32
             + lq * 8;
    __syncthreads();   // drains vmcnt: staged weights visible

    #pragma unroll
    for (int r = 0; r < 3; ++r)
      #pragma unroll
      for (int s = 0; s < 3; ++s) {
        const int rs = r * 3 + s;
        f16x8 bb[2][2];
        #pragma unroll
        for (int jj = 0; jj < 2; ++jj)
          #pragma unroll
          for (int f = 0; f < 2; ++f)
            bb[jj][f] = *reinterpret_cast<const f16x8*>(rb[r + jj] + (f * 16 + s) * 32);
        const int base = rs * 2048 + aswz0;
        const f16x8 a0 = *reinterpret_cast<const f16x8*>(&smem[base]);
        const f16x8 a1 = *reinterpret_cast<const f16x8*>(&smem[base + 512]);
        const f16x8 a2 = *reinterpret_cast<const f16x8*>(&smem[base + 1024]);
        const f16x8 a3 = *reinterpret_cast<const f16x8*>(&smem[base + 1536]);
        #pragma unroll
        for (int jj = 0; jj < 2; ++jj)
          #pragma unroll
          for (int f = 0; f < 2; ++f) {
            acc[0][jj][f] = MFMA16F(a0, bb[jj][f], acc[0][jj][f]);
            acc[1][jj][f] = MFMA16F(a1, bb[jj][f], acc[1][jj][f]);
            acc[2][jj][f] = MFMA16F(a2, bb[jj][f], acc[2][jj][f]);
            acc[3][jj][f] = MFMA16F(a3, bb[jj][f], acc[3][jj][f]);
          }
      }
  }

  // ---- epilogue: bias (+relu for OF16), LDS staging [2][64][72] u16
  // (16B-aligned rows, ~2-way banks), f16 write
  __syncthreads();
  u16* st = smem;                          // 2*64*72 = 9216 u16
  #pragma unroll
  for (int mf = 0; mf < 4; ++mf)
    #pragma unroll
    for (int jj = 0; jj < 2; ++jj)
      #pragma unroll
      for (int f = 0; f < 2; ++f)
        #pragma unroll
        for (int reg = 0; reg < 4; ++reg) {
          const int ocl = mf * 16 + lq * 4 + reg;    // 0..63
          const int px = pxw + f * 16 + lm;
          float v = acc[mf][jj][f][reg] + bias[ocsel * 64 + ocl];
          if (OF16) v = fmaxf(v, 0.f);
          st[(jj * 64 + px) * 72 + ocl] = __builtin_bit_cast(u16, (_Float16)v);
        }
  __syncthreads();
  for (int i = tid; i < 1024; i += 128) {   // 2 rows x 64 px x 8 us8-chunks
    const int o8 = i & 7;
    const int px = (i >> 3) & 63;
    const int row = i >> 9;
    us8 val = *reinterpret_cast<const us8*>(&st[(row * 64 + px) * 72 + o8 * 8]);
    u16* dst;
    if (OF16)
      dst = outp + ((((long)b * H2 + hb + row + 1) * 4 + ocsel * 2 + (o8 >> 2)) * W2
                    + (w0 + px + 1)) * 32 + (o8 & 3) * 8;
    else
      dst = outp + (((long)b * IH + hb + row) * IW + w0 + px) * 128
          + ocsel * 64 + o8 * 8;
    *reinterpret_cast<us8*>(dst) = val;
  }
}

// ---- attention: one block per (b, n). 128 threads. All operands f16.
__global__ __launch_bounds__(128) void attn_k(
    const u16* __restrict__ qf, const u16* __restrict__ kf,
    const u16* __restrict__ zf, const int* __restrict__ u,
    float* __restrict__ out)
{
  constexpr float SCALE = 0.08838834764831845f;  // 128^-0.5
  const int n = blockIdx.x, b = blockIdx.y;
  const int t = threadIdx.x;

  __shared__ float qs[128];
  __shared__ float logit[32];
  __shared__ float el[32];

  int widx = u[b * 4096 + n];
  widx = widx < 0 ? 0 : (widx > 511 ? 511 : widx);

  qs[t] = (float)__builtin_bit_cast(_Float16, qf[((long)b * 4096 + n) * 128 + t]);
  __syncthreads();

  const int h = t >> 2, quad = t & 3;
  const u16* kcol = kf + (((long)b * 32 + h) * 512 + widx) * 128 + quad * 32;
  float p = 0.f;
  #pragma unroll
  for (int j = 0; j < 32; j += 8) {
    f16x8 kv = *reinterpret_cast<const f16x8*>(kcol + j);
    #pragma unroll
    for (int jj = 0; jj < 8; ++jj)
      p = fmaf(qs[quad * 32 + j + jj], (float)kv[jj], p);
  }
  p += __shfl_xor(p, 1);
  p += __shfl_xor(p, 2);
  if (quad == 0) logit[h] = p * SCALE;
  __syncthreads();

  float m = -3.4e38f;
  #pragma unroll
  for (int h2 = 0; h2 < 32; ++h2) m = fmaxf(m, logit[h2]);
  if (t < 32) el[t] = __expf(logit[t] - m);
  __syncthreads();
  float den = 0.f;
  #pragma unroll
  for (int h2 = 0; h2 < 32; ++h2) den += el[h2];

  const u16* zcol = zf + ((long)b * 32 * 512) * 128 + (long)widx * 128 + t;
  float o0 = 0.f, o1 = 0.f, o2 = 0.f, o3 = 0.f;
  #pragma unroll
  for (int h2 = 0; h2 < 32; h2 += 4) {
    o0 = fmaf(el[h2 + 0], (float)__builtin_bit_cast(_Float16, zcol[(long)(h2 + 0) * 512 * 128]), o0);
    o1 = fmaf(el[h2 + 1], (float)__builtin_bit_cast(_Float16, zcol[(long)(h2 + 1) * 512 * 128]), o1);
    o2 = fmaf(el[h2 + 2], (float)__builtin_bit_cast(_Float16, zcol[(long)(h2 + 2) * 512 * 128]), o2);
    o3 = fmaf(el[h2 + 3], (float)__builtin_bit_cast(_Float16, zcol[(long)(h2 + 3) * 512 * 128]), o3);
  }
  out[((long)b * 4096 + n) * 128 + t] = ((o0 + o1) + (o2 + o3)) / den;
}

extern "C" void kernel_launch(void* const* d_in, const int* in_sizes, int n_in,
                              void* d_out, int out_size, void* d_ws, size_t ws_size,
                              hipStream_t stream) {
  const float* x   = (const float*)d_in[0];
  const float* y   = (const float*)d_in[1];
  const float* z   = (const float*)d_in[2];
  const int*   u   = (const int*)  d_in[3];
  const float* wq1 = (const float*)d_in[4];
  const float* bq1 = (const float*)d_in[5];
  const float* wq2 = (const float*)d_in[6];
  const float* bq2 = (const float*)d_in[7];
  const float* wk1 = (const float*)d_in[8];
  const float* bk1 = (const float*)d_in[9];
  const float* wk2 = (const float*)d_in[10];
  const float* bk2 = (const float*)d_in[11];
  float* out = (float*)d_out;
  u16* wsu = (u16*)d_ws;

  // ---- arena (u16 offsets); total 54.2 MB
  u16* ypad  = wsu + 0;           //  8,947,712  [2][34][8][514][32] f16
  u16* xpad  = wsu + 8947712;     //  2,230,272  [2][66][8][66][32]  f16
  u16* t2k   = wsu + 11177984;    //  4,473,856  [2][34][4][514][32] f16
  u16* t1q   = wsu + 15651840;    //  1,115,136  [2][66][4][66][32]  f16
  u16* zf16  = wsu + 16766976;    //  4,194,304  [2][32][512][128]   f16
  u16* k_f16 = wsu + 20961280;    //  4,194,304  [2][32][512][128]   f16
  u16* q_f16 = wsu + 25155584;    //  1,048,576  [2,4096,128]        f16
  u16* wpk_q1 = wsu + 26204160;   //    294,912  (pre-swizzled)
  u16* wpk_q2 = wsu + 26499072;   //    147,456
  u16* wpk_k1 = wsu + 26646528;   //    294,912
  u16* wpk_k2 = wsu + 26941440;   //    147,456  -> end 27,088,896 u16

  prep_k<<<dim3(14847), 256, 0, stream>>>(x, y, z, wq1, wq2, wk1, wk2,
                                          wpk_q1, wpk_q2, wpk_k1, wpk_k2,
                                          ypad, xpad, t2k, t1q, zf16);
  conv_k<8, 1><<<dim3(640), 128, 0, stream>>>(
      ypad, wpk_k1, bk1, t2k, xpad, wpk_q1, bq1, t1q);
  conv_k<4, 0><<<dim3(640), 128, 0, stream>>>(
      t2k, wpk_k2, bk2, k_f16, t1q, wpk_q2, bq2, q_f16);
  attn_k<<<dim3(4096, 2), 128, 0, stream>>>(q_f16, k_f16, zf16, u, out);
}